// Round 1
// baseline (411.322 us; speedup 1.0000x reference)
//
#include <hip/hip_runtime.h>
#include <hip/hip_bf16.h>
#include <math.h>

#define BN 1024
#define DIN 64
#define HD 128
#define EN 8192

// ---------------- init ----------------
__global__ void k_init(int* deg, int* cnt, int* comp, unsigned long long* best, int* mstcnt) {
    int i = blockIdx.x * blockDim.x + threadIdx.x;
    if (i < BN) { deg[i] = 1; cnt[i] = 0; comp[i] = i; best[i] = 0ull; }
    if (i == 0) *mstcnt = 0;
}

__global__ void k_deg(const int* dst, int* deg) {
    int e = blockIdx.x * blockDim.x + threadIdx.x;
    if (e < EN) atomicAdd(&deg[dst[e]], 1);
}

__global__ void k_dinv(const int* deg, float* dinv) {
    int i = blockIdx.x * blockDim.x + threadIdx.x;
    if (i < BN) dinv[i] = 1.0f / sqrtf(fmaxf((float)deg[i], 1e-12f));
}

// deterministic CSR: rank[e] = #earlier edges with same dst
__global__ __launch_bounds__(256) void k_rank(const int* dst, int* rank, int* cnt) {
    __shared__ int sd[EN];
    int tid = threadIdx.x;
    for (int idx = tid; idx < EN; idx += 256) sd[idx] = dst[idx];
    __syncthreads();
    int e = blockIdx.x * 256 + tid;
    if (e >= EN) return;
    int d = sd[e];
    int r = 0;
    for (int q = 0; q < e; q++) r += (sd[q] == d) ? 1 : 0;
    rank[e] = r;
    atomicAdd(&cnt[d], 1);
}

__global__ __launch_bounds__(1024) void k_scan(const int* cnt, int* off) {
    __shared__ int s[BN];
    int c = threadIdx.x;
    s[c] = cnt[c];
    __syncthreads();
    for (int d = 1; d < BN; d <<= 1) {
        int v = (c >= d) ? s[c - d] : 0;
        __syncthreads();
        s[c] += v;
        __syncthreads();
    }
    off[c + 1] = s[c];
    if (c == 0) off[0] = 0;
}

__global__ void k_fill(const int* dst, const int* rank, const int* off, int* slots) {
    int e = blockIdx.x * blockDim.x + threadIdx.x;
    if (e < EN) slots[off[dst[e]] + rank[e]] = e;
}

// out[row][col] = sum_k x[row][k]*W[k][col] (+ bias[col])
__global__ __launch_bounds__(128) void k_mm(const float* x, const float* W, const float* bias,
                                            float* out, int K) {
    __shared__ float xr[HD];
    int row = blockIdx.x, col = threadIdx.x;
    if (col < K) xr[col] = x[row * K + col];
    __syncthreads();
    float acc = bias ? bias[col] : 0.0f;
    for (int k = 0; k < K; k++) acc = fmaf(xr[k], W[k * HD + col], acc);
    out[row * HD + col] = acc;
}

// GCN gather: out[d][t] = relu( sum_edges xw[src]*dinv[src]*dinv[d] + xw[d]*dinv[d]^2 + b[t] )
__global__ __launch_bounds__(128) void k_gather(const float* xw, const float* bvec, const int* src,
                                                const int* slots, const int* off, const int* cnt,
                                                const float* dinv, float* hout) {
    int d = blockIdx.x, t = threadIdx.x;
    float dd = dinv[d];
    float acc = 0.0f;
    int base = off[d], n = cnt[d];
    for (int s = 0; s < n; s++) {
        int e = slots[base + s];
        int sn = src[e];
        acc = fmaf(xw[sn * HD + t], dinv[sn] * dd, acc);
    }
    acc = fmaf(xw[d * HD + t], dd * dd, acc);
    acc += bvec[t];
    hout[d * HD + t] = fmaxf(acc, 0.0f);
}

// scores: S[i][j] = S[j][i] = sum_k relu(A[min][k]+C[max][k])*w2[k] + bs2, diag 0
__global__ __launch_bounds__(256) void k_scores(const float* Aa, const float* Cc,
                                                const float* Ws2, const float* bs2v, float* S) {
    int bi = blockIdx.y, bj = blockIdx.x;
    if (bi > bj) return;
    __shared__ float As[64][68];
    __shared__ float Cs[64][68];
    __shared__ float w2[HD];
    int tid = threadIdx.x;
    int R = bi * 64, Cb = bj * 64;
    if (tid < HD) w2[tid] = Ws2[tid];
    int tx = tid & 15, ty = tid >> 4;
    float acc[4][4] = {};
    for (int half = 0; half < 2; half++) {
        int k0 = half * 64;
        __syncthreads();
        for (int idx = tid; idx < 64 * 64; idx += 256) {
            int row = idx >> 6;
            int kk = idx & 63;
            As[kk][row] = Aa[(R + row) * HD + k0 + kk];
            Cs[kk][row] = Cc[(Cb + row) * HD + k0 + kk];
        }
        __syncthreads();
        for (int kk = 0; kk < 64; kk++) {
            float4 av = *(const float4*)&As[kk][ty * 4];
            float4 cv = *(const float4*)&Cs[kk][tx * 4];
            float wk = w2[k0 + kk];
            float ar[4] = {av.x, av.y, av.z, av.w};
            float cr[4] = {cv.x, cv.y, cv.z, cv.w};
#pragma unroll
            for (int r = 0; r < 4; r++)
#pragma unroll
                for (int q = 0; q < 4; q++) {
                    float tv = fmaxf(ar[r] + cr[q], 0.0f);
                    acc[r][q] = fmaf(tv, wk, acc[r][q]);
                }
        }
    }
    float b2 = bs2v[0];
#pragma unroll
    for (int r = 0; r < 4; r++)
#pragma unroll
        for (int q = 0; q < 4; q++) {
            int gr = R + ty * 4 + r, gc = Cb + tx * 4 + q;
            float v = acc[r][q] + b2;
            if (gr < gc) { S[gr * BN + gc] = v; S[gc * BN + gr] = v; }
            else if (gr == gc) S[gr * BN + gc] = 0.0f;
        }
}

__device__ __forceinline__ unsigned long long edge_key(float w, int i, int j) {
    unsigned u = __float_as_uint(w);
    u = (u & 0x80000000u) ? ~u : (u | 0x80000000u);
    int a = i < j ? i : j, b = i < j ? j : i;
    unsigned packed = (unsigned)(a * BN + b);
    return ((unsigned long long)u << 20) | (unsigned long long)(0xFFFFFu - packed);
}

__global__ __launch_bounds__(256) void k_best(const float* S, const int* comp,
                                              unsigned long long* best) {
    int i = blockIdx.x;
    int ci = comp[i];
    unsigned long long loc = 0ull;
    for (int j = threadIdx.x; j < BN; j += 256) {
        if (comp[j] != ci) {
            unsigned long long key = edge_key(S[i * BN + j], i, j);
            if (key > loc) loc = key;
        }
    }
    __shared__ unsigned long long red[256];
    red[threadIdx.x] = loc;
    __syncthreads();
    for (int s = 128; s > 0; s >>= 1) {
        if (threadIdx.x < s) {
            unsigned long long o = red[threadIdx.x + s];
            if (o > red[threadIdx.x]) red[threadIdx.x] = o;
        }
        __syncthreads();
    }
    if (threadIdx.x == 0 && red[0]) atomicMax(&best[ci], red[0]);
}

__global__ __launch_bounds__(1024) void k_merge(int* comp, unsigned long long* best,
                                                unsigned long long* mst, int* mstcnt) {
    __shared__ int pa[BN], pb[BN];
    int c = threadIdx.x;
    int myComp = comp[c];
    bool root = (myComp == c);
    unsigned long long e = best[c];
    int t = c;
    if (root && e) {
        unsigned packed = 0xFFFFFu - (unsigned)(e & 0xFFFFFu);
        int a = packed >> 10, b = packed & 1023;
        int ca = comp[a], cb = comp[b];
        t = (ca == c) ? cb : ca;
    }
    pa[c] = (root && e) ? t : c;
    __syncthreads();
    bool mutual = root && e && (pa[t] == c);
    int p0 = pa[c];
    if (mutual && c < t) p0 = c;
    __syncthreads();
    pa[c] = p0;
    __syncthreads();
    if (root && e && !(mutual && c > t)) {
        int idx = atomicAdd(mstcnt, 1);
        mst[idx] = e;
    }
    for (int it = 0; it < 10; it++) {
        pb[c] = pa[pa[c]];
        __syncthreads();
        pa[c] = pb[c];
        __syncthreads();
    }
    comp[c] = pa[myComp];
    best[c] = 0ull;
}

__global__ __launch_bounds__(1024) void k_sort(const unsigned long long* mst, float* out, int* pairs) {
    __shared__ unsigned long long s[BN];
    int tid = threadIdx.x;
    s[tid] = (tid < BN - 1) ? mst[tid] : 0ull;
    __syncthreads();
    for (int k = 2; k <= BN; k <<= 1)
        for (int j = k >> 1; j > 0; j >>= 1) {
            int l = tid ^ j;
            if (l > tid) {
                unsigned long long x = s[tid], y = s[l];
                bool up = ((tid & k) == 0);
                if ((x > y) == up) { s[tid] = y; s[l] = x; }
            }
            __syncthreads();
        }
    if (tid < BN - 1) {
        unsigned long long key = s[BN - 1 - tid];  // descending rank tid
        unsigned packed = 0xFFFFFu - (unsigned)(key & 0xFFFFFu);
        int i = packed >> 10, j2 = packed & 1023;
        out[2 * tid] = (float)i;
        out[2 * tid + 1] = (float)j2;
        out[2046 + 2 * tid] = (float)j2;
        out[2046 + 2 * tid + 1] = (float)i;
        pairs[2 * tid] = i;
        pairs[2 * tid + 1] = j2;
    }
}

__global__ __launch_bounds__(128) void k_gamma(const float* h, const int* pairs,
                                               const float* Wg1, const float* bg1,
                                               const float* Wg2, const float* bg2, float* out) {
    int eidx = blockIdx.x;
    __shared__ float hp[2 * HD];
    __shared__ float z1[HD];
    int t = threadIdx.x;
    int i = pairs[2 * eidx], j = pairs[2 * eidx + 1];
    hp[t] = h[i * HD + t];
    hp[HD + t] = h[j * HD + t];
    __syncthreads();
    float acc = bg1[t];
    for (int k = 0; k < 2 * HD; k++) acc = fmaf(hp[k], Wg1[k * HD + t], acc);
    z1[t] = fmaxf(acc, 0.0f);
    __syncthreads();
    if (t < DIN) {
        float g = bg2[t];
        for (int k = 0; k < HD; k++) g = fmaf(z1[k], Wg2[k * DIN + t], g);
        out[4092 + eidx * DIN + t] = tanhf(g);
    }
}

extern "C" void kernel_launch(void* const* d_in, const int* in_sizes, int n_in,
                              void* d_out, int out_size, void* d_ws, size_t ws_size,
                              hipStream_t stream) {
    const float* mu  = (const float*)d_in[0];
    const int*   ei  = (const int*)d_in[1];
    const float* W1  = (const float*)d_in[2];
    const float* b1  = (const float*)d_in[3];
    const float* W2  = (const float*)d_in[4];
    const float* b2  = (const float*)d_in[5];
    const float* Ws1 = (const float*)d_in[6];
    const float* bs1 = (const float*)d_in[7];
    const float* Ws2 = (const float*)d_in[8];
    const float* bs2 = (const float*)d_in[9];
    const float* Wg1 = (const float*)d_in[10];
    const float* bg1 = (const float*)d_in[11];
    const float* Wg2 = (const float*)d_in[12];
    const float* bg2 = (const float*)d_in[13];
    float* out = (float*)d_out;

    const int* src = ei;
    const int* dst = ei + EN;

    char* ws = (char*)d_ws;
    float* S    = (float*)(ws);                     // 4 MiB
    float* xw   = (float*)(ws + 4194304);           // 512 KiB
    float* h1   = (float*)(ws + 4718592);           // 512 KiB
    float* h2   = (float*)(ws + 5242880);           // 512 KiB
    float* Aa   = (float*)(ws + 5767168);           // 512 KiB
    float* Cc   = (float*)(ws + 6291456);           // 512 KiB
    int*   deg  = (int*)(ws + 6815744);
    float* dinv = (float*)(ws + 6819840);
    int*   cnt  = (int*)(ws + 6823936);
    int*   off  = (int*)(ws + 6828032);
    int*   rank = (int*)(ws + 6832384);
    int*   slots= (int*)(ws + 6865152);
    int*   comp = (int*)(ws + 6897920);
    unsigned long long* best = (unsigned long long*)(ws + 6902016);
    unsigned long long* mst  = (unsigned long long*)(ws + 6910208);
    int*   mstcnt = (int*)(ws + 6918400);
    int*   pairs  = (int*)(ws + 6922496);

    k_init<<<4, 256, 0, stream>>>(deg, cnt, comp, best, mstcnt);
    k_deg<<<EN / 256, 256, 0, stream>>>(dst, deg);
    k_dinv<<<4, 256, 0, stream>>>(deg, dinv);
    k_rank<<<EN / 256, 256, 0, stream>>>(dst, rank, cnt);
    k_scan<<<1, 1024, 0, stream>>>(cnt, off);
    k_fill<<<EN / 256, 256, 0, stream>>>(dst, rank, off, slots);

    k_mm<<<BN, HD, 0, stream>>>(mu, W1, nullptr, xw, DIN);
    k_gather<<<BN, HD, 0, stream>>>(xw, b1, src, slots, off, cnt, dinv, h1);
    k_mm<<<BN, HD, 0, stream>>>(h1, W2, nullptr, xw, HD);
    k_gather<<<BN, HD, 0, stream>>>(xw, b2, src, slots, off, cnt, dinv, h2);

    k_mm<<<BN, HD, 0, stream>>>(h2, Ws1, nullptr, Aa, HD);
    k_mm<<<BN, HD, 0, stream>>>(h2, Ws1 + HD * HD, bs1, Cc, HD);

    k_scores<<<dim3(16, 16), 256, 0, stream>>>(Aa, Cc, Ws2, bs2, S);

    for (int r = 0; r < 10; r++) {
        k_best<<<BN, 256, 0, stream>>>(S, comp, best);
        k_merge<<<1, 1024, 0, stream>>>(comp, best, mst, mstcnt);
    }

    k_sort<<<1, 1024, 0, stream>>>(mst, out, pairs);
    k_gamma<<<BN - 1, HD, 0, stream>>>(h2, pairs, Wg1, bg1, Wg2, bg2, out);
}

// Round 2
// 179.721 us; speedup vs baseline: 2.2887x; 2.2887x over previous
//
#include <hip/hip_runtime.h>
#include <hip/hip_bf16.h>
#include <math.h>

#define BN 1024
#define DIN 64
#define HD 128
#define EN 8192
#define SLOTS_STRIDE 64

// ---------------- init ----------------
__global__ void k_init(int* cnt, int* comp, unsigned long long* best, int* mstcnt) {
    int i = blockIdx.x * blockDim.x + threadIdx.x;
    if (i < BN) { cnt[i] = 0; comp[i] = i; best[i] = 0ull; }
    if (i == 0) *mstcnt = 0;
}

// atomic bucket fill (order nondeterministic; fixed by k_finish sort)
__global__ void k_fill(const int* dst, int* cnt, int* slots) {
    int e = blockIdx.x * blockDim.x + threadIdx.x;
    if (e < EN) {
        int d = dst[e];
        int p = atomicAdd(&cnt[d], 1);
        if (p < SLOTS_STRIDE) slots[d * SLOTS_STRIDE + p] = e;
    }
}

// per-node insertion sort by edge id -> deterministic CSR order; also deg/dinv
__global__ __launch_bounds__(128) void k_finish(int* slots, const int* cnt, float* dinv) {
    __shared__ int buf[128][65];
    int tid = threadIdx.x;
    int t = blockIdx.x * 128 + tid;
    int n = cnt[t];
    if (n > SLOTS_STRIDE) n = SLOTS_STRIDE;
    for (int k = 0; k < n; k++) buf[tid][k] = slots[t * SLOTS_STRIDE + k];
    for (int k = 1; k < n; k++) {
        int v = buf[tid][k];
        int q = k - 1;
        while (q >= 0 && buf[tid][q] > v) { buf[tid][q + 1] = buf[tid][q]; q--; }
        buf[tid][q + 1] = v;
    }
    for (int k = 0; k < n; k++) slots[t * SLOTS_STRIDE + k] = buf[tid][k];
    dinv[t] = 1.0f / sqrtf(fmaxf((float)(n + 1), 1e-12f));
}

// out[row][col] = sum_k x[row][k]*W[k][col] (+ bias[col])
__global__ __launch_bounds__(128) void k_mm(const float* x, const float* W, const float* bias,
                                            float* out, int K) {
    __shared__ float xr[HD];
    int row = blockIdx.x, col = threadIdx.x;
    if (col < K) xr[col] = x[row * K + col];
    __syncthreads();
    float acc = bias ? bias[col] : 0.0f;
    for (int k = 0; k < K; k++) acc = fmaf(xr[k], W[k * HD + col], acc);
    out[row * HD + col] = acc;
}

// GCN gather: out[d][t] = relu( sum_edges xw[src]*dinv[src]*dinv[d] + xw[d]*dinv[d]^2 + b[t] )
__global__ __launch_bounds__(128) void k_gather(const float* xw, const float* bvec, const int* src,
                                                const int* slots, const int* cnt,
                                                const float* dinv, float* hout) {
    int d = blockIdx.x, t = threadIdx.x;
    float dd = dinv[d];
    float acc = 0.0f;
    int base = d * SLOTS_STRIDE, n = cnt[d];
    if (n > SLOTS_STRIDE) n = SLOTS_STRIDE;
    for (int s = 0; s < n; s++) {
        int e = slots[base + s];
        int sn = src[e];
        acc = fmaf(xw[sn * HD + t], dinv[sn] * dd, acc);
    }
    acc = fmaf(xw[d * HD + t], dd * dd, acc);
    acc += bvec[t];
    hout[d * HD + t] = fmaxf(acc, 0.0f);
}

// scores: S[i][j] = S[j][i] = sum_k relu(A[min][k]+C[max][k])*w2[k] + bs2, diag 0
__global__ __launch_bounds__(256) void k_scores(const float* Aa, const float* Cc,
                                                const float* Ws2, const float* bs2v, float* S) {
    int bi = blockIdx.y, bj = blockIdx.x;
    if (bi > bj) return;
    __shared__ float As[64][68];
    __shared__ float Cs[64][68];
    __shared__ float w2[HD];
    int tid = threadIdx.x;
    int R = bi * 64, Cb = bj * 64;
    if (tid < HD) w2[tid] = Ws2[tid];
    int tx = tid & 15, ty = tid >> 4;
    float acc[4][4] = {};
    for (int half = 0; half < 2; half++) {
        int k0 = half * 64;
        __syncthreads();
        for (int idx = tid; idx < 64 * 64; idx += 256) {
            int row = idx >> 6;
            int kk = idx & 63;
            As[kk][row] = Aa[(R + row) * HD + k0 + kk];
            Cs[kk][row] = Cc[(Cb + row) * HD + k0 + kk];
        }
        __syncthreads();
        for (int kk = 0; kk < 64; kk++) {
            float4 av = *(const float4*)&As[kk][ty * 4];
            float4 cv = *(const float4*)&Cs[kk][tx * 4];
            float wk = w2[k0 + kk];
            float ar[4] = {av.x, av.y, av.z, av.w};
            float cr[4] = {cv.x, cv.y, cv.z, cv.w};
#pragma unroll
            for (int r = 0; r < 4; r++)
#pragma unroll
                for (int q = 0; q < 4; q++) {
                    float tv = fmaxf(ar[r] + cr[q], 0.0f);
                    acc[r][q] = fmaf(tv, wk, acc[r][q]);
                }
        }
    }
    float b2 = bs2v[0];
#pragma unroll
    for (int r = 0; r < 4; r++)
#pragma unroll
        for (int q = 0; q < 4; q++) {
            int gr = R + ty * 4 + r, gc = Cb + tx * 4 + q;
            float v = acc[r][q] + b2;
            if (gr < gc) { S[gr * BN + gc] = v; S[gc * BN + gr] = v; }
            else if (gr == gc) S[gr * BN + gc] = 0.0f;
        }
}

__device__ __forceinline__ unsigned long long edge_key(float w, int i, int j) {
    unsigned u = __float_as_uint(w);
    u = (u & 0x80000000u) ? ~u : (u | 0x80000000u);
    int a = i < j ? i : j, b = i < j ? j : i;
    unsigned packed = (unsigned)(a * BN + b);
    return ((unsigned long long)u << 20) | (unsigned long long)(0xFFFFFu - packed);
}

__global__ __launch_bounds__(256) void k_best(const float* S, const int* comp,
                                              unsigned long long* best) {
    int i = blockIdx.x;
    int ci = comp[i];
    unsigned long long loc = 0ull;
    for (int j = threadIdx.x; j < BN; j += 256) {
        if (comp[j] != ci) {
            unsigned long long key = edge_key(S[i * BN + j], i, j);
            if (key > loc) loc = key;
        }
    }
    __shared__ unsigned long long red[256];
    red[threadIdx.x] = loc;
    __syncthreads();
    for (int s = 128; s > 0; s >>= 1) {
        if (threadIdx.x < s) {
            unsigned long long o = red[threadIdx.x + s];
            if (o > red[threadIdx.x]) red[threadIdx.x] = o;
        }
        __syncthreads();
    }
    if (threadIdx.x == 0 && red[0]) atomicMax(&best[ci], red[0]);
}

__global__ __launch_bounds__(1024) void k_merge(int* comp, unsigned long long* best,
                                                unsigned long long* mst, int* mstcnt) {
    __shared__ int pa[BN], pb[BN];
    int c = threadIdx.x;
    int myComp = comp[c];
    bool root = (myComp == c);
    unsigned long long e = best[c];
    int t = c;
    if (root && e) {
        unsigned packed = 0xFFFFFu - (unsigned)(e & 0xFFFFFu);
        int a = packed >> 10, b = packed & 1023;
        int ca = comp[a], cb = comp[b];
        t = (ca == c) ? cb : ca;
    }
    pa[c] = (root && e) ? t : c;
    __syncthreads();
    bool mutual = root && e && (pa[t] == c);
    int p0 = pa[c];
    if (mutual && c < t) p0 = c;
    __syncthreads();
    pa[c] = p0;
    __syncthreads();
    if (root && e && !(mutual && c > t)) {
        int idx = atomicAdd(mstcnt, 1);
        mst[idx] = e;
    }
    for (int it = 0; it < 10; it++) {
        pb[c] = pa[pa[c]];
        __syncthreads();
        pa[c] = pb[c];
        __syncthreads();
    }
    comp[c] = pa[myComp];
    best[c] = 0ull;
}

__global__ __launch_bounds__(1024) void k_sort(const unsigned long long* mst, float* out, int* pairs) {
    __shared__ unsigned long long s[BN];
    int tid = threadIdx.x;
    s[tid] = (tid < BN - 1) ? mst[tid] : 0ull;
    __syncthreads();
    for (int k = 2; k <= BN; k <<= 1)
        for (int j = k >> 1; j > 0; j >>= 1) {
            int l = tid ^ j;
            if (l > tid) {
                unsigned long long x = s[tid], y = s[l];
                bool up = ((tid & k) == 0);
                if ((x > y) == up) { s[tid] = y; s[l] = x; }
            }
            __syncthreads();
        }
    if (tid < BN - 1) {
        unsigned long long key = s[BN - 1 - tid];  // descending rank tid
        unsigned packed = 0xFFFFFu - (unsigned)(key & 0xFFFFFu);
        int i = packed >> 10, j2 = packed & 1023;
        out[2 * tid] = (float)i;
        out[2 * tid + 1] = (float)j2;
        out[2046 + 2 * tid] = (float)j2;
        out[2046 + 2 * tid + 1] = (float)i;
        pairs[2 * tid] = i;
        pairs[2 * tid + 1] = j2;
    }
}

__global__ __launch_bounds__(128) void k_gamma(const float* h, const int* pairs,
                                               const float* Wg1, const float* bg1,
                                               const float* Wg2, const float* bg2, float* out) {
    int eidx = blockIdx.x;
    __shared__ float hp[2 * HD];
    __shared__ float z1[HD];
    int t = threadIdx.x;
    int i = pairs[2 * eidx], j = pairs[2 * eidx + 1];
    hp[t] = h[i * HD + t];
    hp[HD + t] = h[j * HD + t];
    __syncthreads();
    float acc = bg1[t];
    for (int k = 0; k < 2 * HD; k++) acc = fmaf(hp[k], Wg1[k * HD + t], acc);
    z1[t] = fmaxf(acc, 0.0f);
    __syncthreads();
    if (t < DIN) {
        float g = bg2[t];
        for (int k = 0; k < HD; k++) g = fmaf(z1[k], Wg2[k * DIN + t], g);
        out[4092 + eidx * DIN + t] = tanhf(g);
    }
}

extern "C" void kernel_launch(void* const* d_in, const int* in_sizes, int n_in,
                              void* d_out, int out_size, void* d_ws, size_t ws_size,
                              hipStream_t stream) {
    const float* mu  = (const float*)d_in[0];
    const int*   ei  = (const int*)d_in[1];
    const float* W1  = (const float*)d_in[2];
    const float* b1  = (const float*)d_in[3];
    const float* W2  = (const float*)d_in[4];
    const float* b2  = (const float*)d_in[5];
    const float* Ws1 = (const float*)d_in[6];
    const float* bs1 = (const float*)d_in[7];
    const float* Ws2 = (const float*)d_in[8];
    const float* bs2 = (const float*)d_in[9];
    const float* Wg1 = (const float*)d_in[10];
    const float* bg1 = (const float*)d_in[11];
    const float* Wg2 = (const float*)d_in[12];
    const float* bg2 = (const float*)d_in[13];
    float* out = (float*)d_out;

    const int* src = ei;
    const int* dst = ei + EN;

    char* ws = (char*)d_ws;
    // Phase-1 arrays (dead before k_scores) alias the S region:
    int*   slots = (int*)(ws);                      // 256 KiB, dies after gather2
    int*   cnt   = (int*)(ws + 262144);             // 4 KiB, dies after gather2
    float* dinv  = (float*)(ws + 266240);           // 4 KiB, dies after gather2
    float* S     = (float*)(ws);                    // 4 MiB, born at k_scores
    float* xw    = (float*)(ws + 4194304);          // 512 KiB
    float* h1    = (float*)(ws + 4718592);          // 512 KiB
    float* h2    = (float*)(ws + 5242880);          // 512 KiB (live until gamma)
    float* Aa    = (float*)(ws + 5767168);          // 512 KiB
    float* Cc    = (float*)(ws + 6291456);          // 512 KiB
    int*   comp  = (int*)(ws + 6815744);            // 4 KiB
    unsigned long long* best = (unsigned long long*)(ws + 6819840); // 8 KiB
    unsigned long long* mst  = (unsigned long long*)(ws + 6828032); // 8 KiB
    int*   mstcnt = (int*)(ws + 6836224);
    int*   pairs  = (int*)(ws + 6840320);           // 8 KiB

    k_init<<<4, 256, 0, stream>>>(cnt, comp, best, mstcnt);
    k_fill<<<EN / 256, 256, 0, stream>>>(dst, cnt, slots);
    k_finish<<<BN / 128, 128, 0, stream>>>(slots, cnt, dinv);

    k_mm<<<BN, HD, 0, stream>>>(mu, W1, nullptr, xw, DIN);
    k_gather<<<BN, HD, 0, stream>>>(xw, b1, src, slots, cnt, dinv, h1);
    k_mm<<<BN, HD, 0, stream>>>(h1, W2, nullptr, xw, HD);
    k_gather<<<BN, HD, 0, stream>>>(xw, b2, src, slots, cnt, dinv, h2);

    k_mm<<<BN, HD, 0, stream>>>(h2, Ws1, nullptr, Aa, HD);
    k_mm<<<BN, HD, 0, stream>>>(h2, Ws1 + HD * HD, bs1, Cc, HD);

    k_scores<<<dim3(16, 16), 256, 0, stream>>>(Aa, Cc, Ws2, bs2, S);

    for (int r = 0; r < 10; r++) {
        k_best<<<BN, 256, 0, stream>>>(S, comp, best);
        k_merge<<<1, 1024, 0, stream>>>(comp, best, mst, mstcnt);
    }

    k_sort<<<1, 1024, 0, stream>>>(mst, out, pairs);
    k_gamma<<<BN - 1, HD, 0, stream>>>(h2, pairs, Wg1, bg1, Wg2, bg2, out);
}